// Round 3
// baseline (1043.362 us; speedup 1.0000x reference)
//
#include <hip/hip_runtime.h>
#include <hip/hip_bf16.h>
#include <cstdint>

#define NROWS 262144
#define HDIM  512
#define NENT  100000
#define SCAN_NBLK ((NENT + 1023) / 1024)

typedef __attribute__((ext_vector_type(4))) float  f32x4;
typedef __attribute__((ext_vector_type(8))) short  bf16x8;

static __device__ __forceinline__ unsigned short f2bf(float x) {
    unsigned u = __float_as_uint(x);
    u += 0x7FFF + ((u >> 16) & 1);          // round-to-nearest-even
    return (unsigned short)(u >> 16);
}

// Pack W ([512][1024] row-major, y = x @ W.T) into bf16 MFMA *A*-fragment order:
// for (ntile, kt32): lane l holds A[m = nt*16+(l&15)][k = kt*32+(l>>4)*8+j].
__global__ void pack_w_kernel(const float* __restrict__ W, unsigned short* __restrict__ Wp) {
    int g    = blockIdx.x * 256 + threadIdx.x;   // 65536 total
    int lane = g & 63;
    int task = g >> 6;                            // 0..1023 = nt*32 + kt
    int nt   = task >> 5;
    int kt   = task & 31;
    int col  = nt * 16 + (lane & 15);
    int k    = kt * 32 + ((lane >> 4) << 3);
    const float* src = W + (size_t)col * 1024 + k;
    f32x4 v0 = *(const f32x4*)(src);
    f32x4 v1 = *(const f32x4*)(src + 4);
    bf16x8 ov;
#pragma unroll
    for (int i = 0; i < 4; ++i) {
        ov[i]     = (short)f2bf(v0[i]);
        ov[4 + i] = (short)f2bf(v1[i]);
    }
    *(bf16x8*)(Wp + (size_t)g * 8) = ov;
}

// ---- CSR build: counts -> 2-level exclusive scan -> fill row indices ----
__global__ __launch_bounds__(256) void count_kernel(const int* __restrict__ ids,
                                                    unsigned* __restrict__ counts) {
    int r = blockIdx.x * 256 + threadIdx.x;
    if (r < NROWS) atomicAdd(&counts[ids[r]], 1u);
}

__global__ __launch_bounds__(1024) void scan1_kernel(const unsigned* __restrict__ counts,
                                                     unsigned* __restrict__ off,
                                                     unsigned* __restrict__ bsums) {
    __shared__ unsigned tmp[1024];
    int i = blockIdx.x * 1024 + threadIdx.x;
    unsigned v = (i < NENT) ? counts[i] : 0u;
    tmp[threadIdx.x] = v;
    __syncthreads();
#pragma unroll
    for (int o = 1; o < 1024; o <<= 1) {
        unsigned a = (threadIdx.x >= o) ? tmp[threadIdx.x - o] : 0u;
        __syncthreads();
        tmp[threadIdx.x] += a;
        __syncthreads();
    }
    if (i < NENT) off[i] = tmp[threadIdx.x] - v;     // block-local exclusive
    if (threadIdx.x == 1023) bsums[blockIdx.x] = tmp[1023];
}

__global__ void scan2_kernel(unsigned* __restrict__ bsums) {
    if (threadIdx.x == 0 && blockIdx.x == 0) {
        unsigned s = 0;
        for (int i = 0; i < SCAN_NBLK; ++i) { unsigned t = bsums[i]; bsums[i] = s; s += t; }
    }
}

__global__ __launch_bounds__(1024) void scan3_kernel(unsigned* __restrict__ off,
                                                     const unsigned* __restrict__ bsums,
                                                     unsigned* __restrict__ cursor) {
    int i = blockIdx.x * 1024 + threadIdx.x;
    if (i < NENT) {
        unsigned o = off[i] + bsums[blockIdx.x];
        off[i] = o;
        cursor[i] = o;
    }
    if (i == 0) off[NENT] = NROWS;
}

__global__ __launch_bounds__(256) void fill_kernel(const int* __restrict__ ids,
                                                   unsigned* __restrict__ cursor,
                                                   int* __restrict__ rowidx) {
    int r = blockIdx.x * 256 + threadIdx.x;
    if (r < NROWS) {
        unsigned p = atomicAdd(&cursor[ids[r]], 1u);
        rowidx[p] = r;
    }
}

// Fused gate path: 64 rows/block x full 512 cols, K=1024 (emb | LN(state)).
// A = W fragment, B = x fragment -> lane owns 4 consecutive out columns.
// Pipelined K loop: double-buffered LDS, ONE barrier per K-step, x[ks+1]
// global loads issued before the MFMA cluster (latency hides under MFMA).
__global__ __launch_bounds__(512, 4) void fuse_kernel(
    const float* __restrict__ emb, const float* __restrict__ slow,
    const unsigned short* __restrict__ Wp, const float* __restrict__ bias,
    const int* __restrict__ ids, float* __restrict__ out)
{
    __shared__ unsigned short aLds[2][8 * 512];   // 2 bufs x 8 frag-tiles, 16B/lane
    __shared__ float muS[64], rsS[64], actS[64], bS[512];
    __shared__ int idS[64];

    const int t    = threadIdx.x;
    const int w    = t >> 6;
    const int lane = t & 63;
    const int brow = blockIdx.x * 64;

    if (t < 128) ((f32x4*)bS)[t] = ((const f32x4*)bias)[t];

    // ---- phase 0: per-row LN stats + is_active ----
    for (int rr = 0; rr < 8; ++rr) {
        int row = w * 8 + rr;
        int id  = ids[brow + row];
        const float* sp = slow + (size_t)id * HDIM;
        f32x4 v0 = ((const f32x4*)sp)[lane * 2];
        f32x4 v1 = ((const f32x4*)sp)[lane * 2 + 1];
        float s = 0.f, s2 = 0.f, sa = 0.f;
#pragma unroll
        for (int i = 0; i < 4; ++i) {
            s  += v0[i] + v1[i];
            s2 += v0[i] * v0[i] + v1[i] * v1[i];
            sa += fabsf(v0[i]) + fabsf(v1[i]);
        }
#pragma unroll
        for (int m = 32; m >= 1; m >>= 1) {
            s  += __shfl_xor(s, m);
            s2 += __shfl_xor(s2, m);
            sa += __shfl_xor(sa, m);
        }
        if (lane == 0) {
            float mu  = s * (1.f / HDIM);
            float var = s2 * (1.f / HDIM) - mu * mu;
            muS[row]  = mu;
            rsS[row]  = rsqrtf(var + 1e-5f);
            actS[row] = (sa > 1e-6f) ? 1.f : 0.f;
            idS[row]  = id;
        }
    }
    __syncthreads();

    const int rowS = t >> 3;            // staging row 0..63
    const int kc   = t & 7;             // 8-float k-chunk within BK=64
    const float* embRow = emb + (size_t)(brow + rowS) * HDIM;
    const float* stRow  = slow + (size_t)idS[rowS] * HDIM;
    const float muR = muS[rowS], rsR = rsS[rowS];

    // swizzled staging position: pos = kg*16 + (rl ^ (kg<<1))
    const int rt_s = rowS >> 4, rl_s = rowS & 15;
    const int kt_s = kc >> 2,  kg_s = kc & 3;
    const int aOff = (kt_s * 4 + rt_s) * 512 + (kg_s * 16 + (rl_s ^ (kg_s << 1))) * 8;
    const int kgr = lane >> 4, rlr = lane & 15;
    const int posr = kgr * 16 + (rlr ^ (kgr << 1));

    const int c0 = w * 64;
    f32x4 zero4 = {0.f, 0.f, 0.f, 0.f};
    f32x4 acc[4][4];                    // [rt = x-row tile][ct = gate-col tile]
#pragma unroll
    for (int i = 0; i < 4; ++i)
#pragma unroll
        for (int j = 0; j < 4; ++j) acc[i][j] = zero4;

#define LOAD_X(ks, x0, x1)                                            \
    {   int kb = (ks) * 64 + kc * 8;                                  \
        if ((ks) < 8) {                                               \
            x0 = *(const f32x4*)(embRow + kb);                        \
            x1 = *(const f32x4*)(embRow + kb + 4);                    \
        } else {                                                      \
            x0 = *(const f32x4*)(stRow + kb - 512);                   \
            x1 = *(const f32x4*)(stRow + kb - 512 + 4);               \
        }                                                             \
    }

#define PACK_STORE(ks, x0, x1, buf)                                   \
    {   f32x4 y0 = x0, y1 = x1;                                       \
        if ((ks) >= 8) {                                              \
            _Pragma("unroll")                                         \
            for (int i = 0; i < 4; ++i) {                             \
                y0[i] = (y0[i] - muR) * rsR;                          \
                y1[i] = (y1[i] - muR) * rsR;                          \
            }                                                         \
        }                                                             \
        bf16x8 av;                                                    \
        _Pragma("unroll")                                             \
        for (int i = 0; i < 4; ++i) {                                 \
            av[i]     = (short)f2bf(y0[i]);                           \
            av[4 + i] = (short)f2bf(y1[i]);                           \
        }                                                             \
        *(bf16x8*)&aLds[buf][aOff] = av;                              \
    }

    {   f32x4 p0, p1;
        LOAD_X(0, p0, p1);
        PACK_STORE(0, p0, p1, 0);
    }
    __syncthreads();

    for (int ks = 0; ks < 16; ++ks) {
        const int cur = ks & 1;
        f32x4 n0, n1;
        if (ks < 15) LOAD_X(ks + 1, n0, n1);       // issue early: hides under MFMA

#pragma unroll
        for (int kk = 0; kk < 2; ++kk) {
            bf16x8 a0 = *(const bf16x8*)&aLds[cur][(kk * 4 + 0) * 512 + posr * 8];
            bf16x8 a1 = *(const bf16x8*)&aLds[cur][(kk * 4 + 1) * 512 + posr * 8];
            bf16x8 a2 = *(const bf16x8*)&aLds[cur][(kk * 4 + 2) * 512 + posr * 8];
            bf16x8 a3 = *(const bf16x8*)&aLds[cur][(kk * 4 + 3) * 512 + posr * 8];
            int kt32 = ks * 2 + kk;
#pragma unroll
            for (int ct = 0; ct < 4; ++ct) {
                int ntile = (c0 >> 4) + ct;
                bf16x8 bfr = *(const bf16x8*)(Wp + ((size_t)(ntile * 32 + kt32) * 64 + lane) * 8);
                acc[0][ct] = __builtin_amdgcn_mfma_f32_16x16x32_bf16(bfr, a0, acc[0][ct], 0, 0, 0);
                acc[1][ct] = __builtin_amdgcn_mfma_f32_16x16x32_bf16(bfr, a1, acc[1][ct], 0, 0, 0);
                acc[2][ct] = __builtin_amdgcn_mfma_f32_16x16x32_bf16(bfr, a2, acc[2][ct], 0, 0, 0);
                acc[3][ct] = __builtin_amdgcn_mfma_f32_16x16x32_bf16(bfr, a3, acc[3][ct], 0, 0, 0);
            }
        }

        if (ks < 15) PACK_STORE(ks + 1, n0, n1, cur ^ 1);
        __syncthreads();   // write(ks+1) visible before MFMA(ks+1); also gates
                           // next write-after-read (all waves past MFMA(ks))
    }
#undef LOAD_X
#undef PACK_STORE

    // ---- epilogue: sigmoid, fuse, vectorized f32x4 writes ----
#pragma unroll
    for (int rt = 0; rt < 4; ++rt) {
        int rowl = rt * 16 + (lane & 15);
        int grow = brow + rowl;
        int id   = idS[rowl];
        float mu = muS[rowl], rs = rsS[rowl], act = actS[rowl];
        const float* embP  = emb  + (size_t)grow * HDIM;
        const float* slowP = slow + (size_t)id * HDIM;
        float*       outP  = out  + (size_t)grow * HDIM;
#pragma unroll
        for (int ct = 0; ct < 4; ++ct) {
            int col0 = c0 + ct * 16 + ((lane >> 4) << 2);
            f32x4 bv = *(const f32x4*)&bS[col0];
            f32x4 ev = *(const f32x4*)(embP + col0);
            f32x4 sv = *(const f32x4*)(slowP + col0);
            f32x4 o;
#pragma unroll
            for (int r = 0; r < 4; ++r) {
                float logit = acc[rt][ct][r] + bv[r];
                float z  = 1.f / (1.f + __expf(-logit));
                float h  = (sv[r] - mu) * rs;
                float fused = z * ev[r] + (1.f - z) * h;
                o[r] = (act > 0.f) ? fused : ev[r];
            }
            *(f32x4*)(outP + col0) = o;
        }
    }
}

// Per-entity: gather its rows from `out` (CSR), mean -> EMA fast, norm-gated slow.
__global__ __launch_bounds__(256) void finalize_kernel(
    const float* __restrict__ fast, const float* __restrict__ slow,
    const float* __restrict__ out, const unsigned* __restrict__ off,
    const int* __restrict__ rowidx, float* __restrict__ nf, float* __restrict__ ns)
{
    int e = blockIdx.x * 4 + (threadIdx.x >> 6);
    if (e >= NENT) return;
    int lane = threadIdx.x & 63;
    size_t base = (size_t)e * HDIM + lane * 8;

    f32x4 f0 = *(const f32x4*)(fast + base), f1 = *(const f32x4*)(fast + base + 4);
    f32x4 l0 = *(const f32x4*)(slow + base), l1 = *(const f32x4*)(slow + base + 4);

    unsigned o0 = off[e], o1 = off[e + 1];
    int c = (int)(o1 - o0);

    if (c == 0) {
        *(f32x4*)(nf + base)     = f0;
        *(f32x4*)(nf + base + 4) = f1;
        *(f32x4*)(ns + base)     = l0;
        *(f32x4*)(ns + base + 4) = l1;
        return;
    }

    f32x4 s0 = {0.f, 0.f, 0.f, 0.f}, s1 = {0.f, 0.f, 0.f, 0.f};
    for (int j = 0; j < c; ++j) {
        int r = rowidx[o0 + j];
        const float* p = out + (size_t)r * HDIM + lane * 8;
        s0 += *(const f32x4*)p;
        s1 += *(const f32x4*)(p + 4);
    }

    float inv = 0.5f / (float)c;          // ALPHA / count
    f32x4 n0, n1, d0, d1;
    float ss = 0.f;
#pragma unroll
    for (int i = 0; i < 4; ++i) {
        n0[i] = 0.5f * f0[i] + s0[i] * inv;
        n1[i] = 0.5f * f1[i] + s1[i] * inv;
        d0[i] = n0[i] - l0[i]; ss += d0[i] * d0[i];
        d1[i] = n1[i] - l1[i]; ss += d1[i] * d1[i];
    }
#pragma unroll
    for (int m = 32; m >= 1; m >>= 1) ss += __shfl_xor(ss, m);
    float delta = sqrtf(ss);
    float gate  = 1.f / (1.f + expf(-5.f * (delta - 0.5f)));

    f32x4 o0v, o1v;
#pragma unroll
    for (int i = 0; i < 4; ++i) {
        o0v[i] = l0[i] + gate * d0[i];
        o1v[i] = l1[i] + gate * d1[i];
    }
    *(f32x4*)(nf + base)     = n0;
    *(f32x4*)(nf + base + 4) = n1;
    *(f32x4*)(ns + base)     = o0v;
    *(f32x4*)(ns + base + 4) = o1v;
}

extern "C" void kernel_launch(void* const* d_in, const int* in_sizes, int n_in,
                              void* d_out, int out_size, void* d_ws, size_t ws_size,
                              hipStream_t stream) {
    const float* emb  = (const float*)d_in[0];
    const float* slow = (const float*)d_in[1];
    const float* fast = (const float*)d_in[2];
    const float* W    = (const float*)d_in[3];
    const float* bias = (const float*)d_in[4];
    const int*   ids  = (const int*)d_in[5];

    float* out = (float*)d_out;
    float* nf  = out + (size_t)NROWS * HDIM;
    float* ns  = nf + (size_t)NENT * HDIM;

    // ws layout: Wp 1 MiB | counts/cursor 400 KB | offsets 400 KB | bsums | rowidx 1 MiB
    unsigned short* Wp   = (unsigned short*)d_ws;
    unsigned* counts     = (unsigned*)((char*)d_ws + (1u << 20));            // reused as cursor
    unsigned* off        = (unsigned*)((char*)d_ws + (1u << 20) + 512 * 1024);
    unsigned* bsums      = (unsigned*)((char*)d_ws + (2u << 20));
    int*      rowidx     = (int*)((char*)d_ws + (2u << 20) + 4096);

    hipMemsetAsync(counts, 0, (size_t)NENT * sizeof(unsigned), stream);

    pack_w_kernel<<<256, 256, 0, stream>>>(W, Wp);
    count_kernel<<<NROWS / 256, 256, 0, stream>>>(ids, counts);
    scan1_kernel<<<SCAN_NBLK, 1024, 0, stream>>>(counts, off, bsums);
    scan2_kernel<<<1, 64, 0, stream>>>(bsums);
    scan3_kernel<<<SCAN_NBLK, 1024, 0, stream>>>(off, bsums, counts);
    fill_kernel<<<NROWS / 256, 256, 0, stream>>>(ids, counts, rowidx);
    fuse_kernel<<<NROWS / 64, 512, 0, stream>>>(emb, slow, Wp, bias, ids, out);
    finalize_kernel<<<(NENT + 3) / 4, 256, 0, stream>>>(fast, slow, out, off, rowidx, nf, ns);
}

// Round 5
// 979.724 us; speedup vs baseline: 1.0650x; 1.0650x over previous
//
#include <hip/hip_runtime.h>
#include <hip/hip_bf16.h>
#include <cstdint>

#define NROWS 262144
#define HDIM  512
#define NENT  100000
#define SCAN_NBLK ((NENT + 1023) / 1024)

typedef __attribute__((ext_vector_type(4))) float  f32x4;
typedef __attribute__((ext_vector_type(8))) short  bf16x8;

static __device__ __forceinline__ unsigned short f2bf(float x) {
    unsigned u = __float_as_uint(x);
    u += 0x7FFF + ((u >> 16) & 1);          // round-to-nearest-even
    return (unsigned short)(u >> 16);
}

// Pack W ([512][1024] row-major, y = x @ W.T) into bf16 MFMA *A*-fragment order:
// for (ntile, kt32): lane l holds A[m = nt*16+(l&15)][k = kt*32+(l>>4)*8+j].
__global__ void pack_w_kernel(const float* __restrict__ W, unsigned short* __restrict__ Wp) {
    int g    = blockIdx.x * 256 + threadIdx.x;   // 65536 total
    int lane = g & 63;
    int task = g >> 6;                            // 0..1023 = nt*32 + kt
    int nt   = task >> 5;
    int kt   = task & 31;
    int col  = nt * 16 + (lane & 15);
    int k    = kt * 32 + ((lane >> 4) << 3);
    const float* src = W + (size_t)col * 1024 + k;
    f32x4 v0 = *(const f32x4*)(src);
    f32x4 v1 = *(const f32x4*)(src + 4);
    bf16x8 ov;
#pragma unroll
    for (int i = 0; i < 4; ++i) {
        ov[i]     = (short)f2bf(v0[i]);
        ov[4 + i] = (short)f2bf(v1[i]);
    }
    *(bf16x8*)(Wp + (size_t)g * 8) = ov;
}

// ---- CSR build: counts -> 2-level exclusive scan -> fill row indices ----
__global__ __launch_bounds__(256) void count_kernel(const int* __restrict__ ids,
                                                    unsigned* __restrict__ counts) {
    int r = blockIdx.x * 256 + threadIdx.x;
    if (r < NROWS) atomicAdd(&counts[ids[r]], 1u);
}

__global__ __launch_bounds__(1024) void scan1_kernel(const unsigned* __restrict__ counts,
                                                     unsigned* __restrict__ off,
                                                     unsigned* __restrict__ bsums) {
    __shared__ unsigned tmp[1024];
    int i = blockIdx.x * 1024 + threadIdx.x;
    unsigned v = (i < NENT) ? counts[i] : 0u;
    tmp[threadIdx.x] = v;
    __syncthreads();
#pragma unroll
    for (int o = 1; o < 1024; o <<= 1) {
        unsigned a = (threadIdx.x >= o) ? tmp[threadIdx.x - o] : 0u;
        __syncthreads();
        tmp[threadIdx.x] += a;
        __syncthreads();
    }
    if (i < NENT) off[i] = tmp[threadIdx.x] - v;     // block-local exclusive
    if (threadIdx.x == 1023) bsums[blockIdx.x] = tmp[1023];
}

__global__ void scan2_kernel(unsigned* __restrict__ bsums) {
    if (threadIdx.x == 0 && blockIdx.x == 0) {
        unsigned s = 0;
        for (int i = 0; i < SCAN_NBLK; ++i) { unsigned t = bsums[i]; bsums[i] = s; s += t; }
    }
}

__global__ __launch_bounds__(1024) void scan3_kernel(unsigned* __restrict__ off,
                                                     const unsigned* __restrict__ bsums,
                                                     unsigned* __restrict__ cursor) {
    int i = blockIdx.x * 1024 + threadIdx.x;
    if (i < NENT) {
        unsigned o = off[i] + bsums[blockIdx.x];
        off[i] = o;
        cursor[i] = o;
    }
    if (i == 0) off[NENT] = NROWS;
}

__global__ __launch_bounds__(256) void fill_kernel(const int* __restrict__ ids,
                                                   unsigned* __restrict__ cursor,
                                                   int* __restrict__ rowidx) {
    int r = blockIdx.x * 256 + threadIdx.x;
    if (r < NROWS) {
        unsigned p = atomicAdd(&cursor[ids[r]], 1u);
        rowidx[p] = r;
    }
}

// Fused gate path: 64 rows/block x 512 cols, K=1024 = [LN(state) | emb]
// (state half FIRST so the epilogue's emb re-read is L2-warm).
// NOTE the K-permutation: x phases 0..3 feed LN(state) -> must use W kt32
// 16..31; phases 4..7 feed emb -> W kt32 0..15. (R4 bug: used ph*4+kk.)
// 1024 threads = 16 waves, each wave 64 rows x 32 cols -> acc = 4x2 f32x4.
// BK=128 per phase, 8 phases, ONE barrier per phase. Per phase: issue 8 W
// frags (oldest -> one L2 wait), then next-phase x loads (youngest), then
// 32 MFMA, then pack.
__global__ __launch_bounds__(1024) void fuse_kernel(
    const float* __restrict__ emb, const float* __restrict__ slow,
    const unsigned short* __restrict__ Wp, const float* __restrict__ bias,
    const int* __restrict__ ids, float* __restrict__ out)
{
    __shared__ unsigned short aLds[2][16 * 512];   // 2 bufs x 16 frag-tiles (16 KB each)
    __shared__ float muS[64], rsS[64], actS[64], bS[512];
    __shared__ int idS[64];

    const int t    = threadIdx.x;
    const int w    = t >> 6;          // 0..15
    const int lane = t & 63;
    const int brow = blockIdx.x * 64;

    if (t < 128) ((f32x4*)bS)[t] = ((const f32x4*)bias)[t];

    // ---- phase 0: per-row LN stats + is_active (16 waves x 4 rows) ----
    for (int rr = 0; rr < 4; ++rr) {
        int row = w * 4 + rr;
        int id  = ids[brow + row];
        const float* sp = slow + (size_t)id * HDIM;
        f32x4 v0 = ((const f32x4*)sp)[lane * 2];
        f32x4 v1 = ((const f32x4*)sp)[lane * 2 + 1];
        float s = 0.f, s2 = 0.f, sa = 0.f;
#pragma unroll
        for (int i = 0; i < 4; ++i) {
            s  += v0[i] + v1[i];
            s2 += v0[i] * v0[i] + v1[i] * v1[i];
            sa += fabsf(v0[i]) + fabsf(v1[i]);
        }
#pragma unroll
        for (int m = 32; m >= 1; m >>= 1) {
            s  += __shfl_xor(s, m);
            s2 += __shfl_xor(s2, m);
            sa += __shfl_xor(sa, m);
        }
        if (lane == 0) {
            float mu  = s * (1.f / HDIM);
            float var = s2 * (1.f / HDIM) - mu * mu;
            muS[row]  = mu;
            rsS[row]  = rsqrtf(var + 1e-5f);
            actS[row] = (sa > 1e-6f) ? 1.f : 0.f;
            idS[row]  = id;
        }
    }
    __syncthreads();

    const int rowS = t >> 4;            // staging row 0..63
    const int c    = t & 15;            // 8-float k-chunk within BK=128
    const float* embRow = emb + (size_t)(brow + rowS) * HDIM;
    const float* stRow  = slow + (size_t)idS[rowS] * HDIM;
    const float muR = muS[rowS], rsR = rsS[rowS];

    // staging fragment address: tile = (c>>2)*4 + rowS>>4, pos = kg*16 + (rl^(kg<<1))
    const int kg_s = c & 3;
    const int aOff = ((c >> 2) * 4 + (rowS >> 4)) * 512 +
                     (kg_s * 16 + ((rowS & 15) ^ (kg_s << 1))) * 8;
    const int kgr = lane >> 4, rlr = lane & 15;
    const int posr = kgr * 16 + (rlr ^ (kgr << 1));

    f32x4 zero4 = {0.f, 0.f, 0.f, 0.f};
    f32x4 acc[4][2];                    // [rt = x-row tile][ct = gate-col tile]
#pragma unroll
    for (int i = 0; i < 4; ++i)
#pragma unroll
        for (int j = 0; j < 2; ++j) acc[i][j] = zero4;

    // K-order: phase 0..3 = state (LN applied), phase 4..7 = emb.
#define LOAD_X(ph, x0, x1)                                              \
    {   const float* base = ((ph) < 4) ? (stRow + (ph) * 128 + c * 8)   \
                                       : (embRow + ((ph) - 4) * 128 + c * 8); \
        x0 = *(const f32x4*)(base);                                     \
        x1 = *(const f32x4*)(base + 4);                                 \
    }

#define PACK_STORE(ph, x0, x1, buf)                                     \
    {   f32x4 y0 = x0, y1 = x1;                                         \
        if ((ph) < 4) {                                                 \
            _Pragma("unroll")                                           \
            for (int i = 0; i < 4; ++i) {                               \
                y0[i] = (y0[i] - muR) * rsR;                            \
                y1[i] = (y1[i] - muR) * rsR;                            \
            }                                                           \
        }                                                               \
        bf16x8 av;                                                      \
        _Pragma("unroll")                                               \
        for (int i = 0; i < 4; ++i) {                                   \
            av[i]     = (short)f2bf(y0[i]);                             \
            av[4 + i] = (short)f2bf(y1[i]);                             \
        }                                                               \
        *(bf16x8*)&aLds[buf][aOff] = av;                                \
    }

    {   f32x4 p0, p1;
        LOAD_X(0, p0, p1);
        PACK_STORE(0, p0, p1, 0);
    }
    __syncthreads();

    for (int ph = 0; ph < 8; ++ph) {
        const int cur = ph & 1;
        // W k-tile base matching the permuted x order: state phases use the
        // second half of W's K (kt32 16..31), emb phases the first half.
        const int ktW = (ph < 4) ? (16 + ph * 4) : ((ph - 4) * 4);

        // (1) issue all 8 W fragments for this phase (oldest VMEM ops ->
        //     first MFMA waits for wf[0] only; rest land during the cluster)
        bf16x8 wf[8];
#pragma unroll
        for (int kk = 0; kk < 4; ++kk)
#pragma unroll
            for (int ct = 0; ct < 2; ++ct)
                wf[kk * 2 + ct] = *(const bf16x8*)(
                    Wp + ((size_t)((w * 2 + ct) * 32 + ktW + kk) * 64 + lane) * 8);

        // (2) issue next-phase x loads (youngest -> never drained by W waits)
        f32x4 nx0, nx1;
        if (ph < 7) LOAD_X(ph + 1, nx0, nx1);

        // (3) MFMA cluster: 4 kk-groups x (4 ds_read + 8 MFMA)
#pragma unroll
        for (int kk = 0; kk < 4; ++kk) {
            bf16x8 a0 = *(const bf16x8*)&aLds[cur][(kk * 4 + 0) * 512 + posr * 8];
            bf16x8 a1 = *(const bf16x8*)&aLds[cur][(kk * 4 + 1) * 512 + posr * 8];
            bf16x8 a2 = *(const bf16x8*)&aLds[cur][(kk * 4 + 2) * 512 + posr * 8];
            bf16x8 a3 = *(const bf16x8*)&aLds[cur][(kk * 4 + 3) * 512 + posr * 8];
#pragma unroll
            for (int ct = 0; ct < 2; ++ct) {
                acc[0][ct] = __builtin_amdgcn_mfma_f32_16x16x32_bf16(wf[kk * 2 + ct], a0, acc[0][ct], 0, 0, 0);
                acc[1][ct] = __builtin_amdgcn_mfma_f32_16x16x32_bf16(wf[kk * 2 + ct], a1, acc[1][ct], 0, 0, 0);
                acc[2][ct] = __builtin_amdgcn_mfma_f32_16x16x32_bf16(wf[kk * 2 + ct], a2, acc[2][ct], 0, 0, 0);
                acc[3][ct] = __builtin_amdgcn_mfma_f32_16x16x32_bf16(wf[kk * 2 + ct], a3, acc[3][ct], 0, 0, 0);
            }
        }

        // (4) pack next tile into the other buffer; x latency covered by (3)
        if (ph < 7) PACK_STORE(ph + 1, nx0, nx1, cur ^ 1);
        __syncthreads();
    }
#undef LOAD_X
#undef PACK_STORE

    // ---- epilogue: sigmoid, fuse, vectorized f32x4 writes ----
    const int c0 = w * 32;
#pragma unroll
    for (int rt = 0; rt < 4; ++rt) {
        int rowl = rt * 16 + (lane & 15);
        int grow = brow + rowl;
        int id   = idS[rowl];
        float mu = muS[rowl], rs = rsS[rowl], act = actS[rowl];
        const float* embP  = emb  + (size_t)grow * HDIM;
        const float* slowP = slow + (size_t)id * HDIM;
        float*       outP  = out  + (size_t)grow * HDIM;
#pragma unroll
        for (int ct = 0; ct < 2; ++ct) {
            int col0 = c0 + ct * 16 + ((lane >> 4) << 2);
            f32x4 bv = *(const f32x4*)&bS[col0];
            f32x4 ev = *(const f32x4*)(embP + col0);
            f32x4 sv = *(const f32x4*)(slowP + col0);
            f32x4 o;
#pragma unroll
            for (int r = 0; r < 4; ++r) {
                float logit = acc[rt][ct][r] + bv[r];
                float z  = 1.f / (1.f + __expf(-logit));
                float h  = (sv[r] - mu) * rs;
                float fused = z * ev[r] + (1.f - z) * h;
                o[r] = (act > 0.f) ? fused : ev[r];
            }
            *(f32x4*)(outP + col0) = o;
        }
    }
}

// Per-entity: gather its rows from `out` (CSR), mean -> EMA fast, norm-gated slow.
__global__ __launch_bounds__(256) void finalize_kernel(
    const float* __restrict__ fast, const float* __restrict__ slow,
    const float* __restrict__ out, const unsigned* __restrict__ off,
    const int* __restrict__ rowidx, float* __restrict__ nf, float* __restrict__ ns)
{
    int e = blockIdx.x * 4 + (threadIdx.x >> 6);
    if (e >= NENT) return;
    int lane = threadIdx.x & 63;
    size_t base = (size_t)e * HDIM + lane * 8;

    f32x4 f0 = *(const f32x4*)(fast + base), f1 = *(const f32x4*)(fast + base + 4);
    f32x4 l0 = *(const f32x4*)(slow + base), l1 = *(const f32x4*)(slow + base + 4);

    unsigned o0 = off[e], o1 = off[e + 1];
    int c = (int)(o1 - o0);

    if (c == 0) {
        *(f32x4*)(nf + base)     = f0;
        *(f32x4*)(nf + base + 4) = f1;
        *(f32x4*)(ns + base)     = l0;
        *(f32x4*)(ns + base + 4) = l1;
        return;
    }

    f32x4 s0 = {0.f, 0.f, 0.f, 0.f}, s1 = {0.f, 0.f, 0.f, 0.f};
    for (int j = 0; j < c; ++j) {
        int r = rowidx[o0 + j];
        const float* p = out + (size_t)r * HDIM + lane * 8;
        s0 += *(const f32x4*)p;
        s1 += *(const f32x4*)(p + 4);
    }

    float inv = 0.5f / (float)c;          // ALPHA / count
    f32x4 n0, n1, d0, d1;
    float ss = 0.f;
#pragma unroll
    for (int i = 0; i < 4; ++i) {
        n0[i] = 0.5f * f0[i] + s0[i] * inv;
        n1[i] = 0.5f * f1[i] + s1[i] * inv;
        d0[i] = n0[i] - l0[i]; ss += d0[i] * d0[i];
        d1[i] = n1[i] - l1[i]; ss += d1[i] * d1[i];
    }
#pragma unroll
    for (int m = 32; m >= 1; m >>= 1) ss += __shfl_xor(ss, m);
    float delta = sqrtf(ss);
    float gate  = 1.f / (1.f + expf(-5.f * (delta - 0.5f)));

    f32x4 o0v, o1v;
#pragma unroll
    for (int i = 0; i < 4; ++i) {
        o0v[i] = l0[i] + gate * d0[i];
        o1v[i] = l1[i] + gate * d1[i];
    }
    *(f32x4*)(nf + base)     = n0;
    *(f32x4*)(nf + base + 4) = n1;
    *(f32x4*)(ns + base)     = o0v;
    *(f32x4*)(ns + base + 4) = o1v;
}

extern "C" void kernel_launch(void* const* d_in, const int* in_sizes, int n_in,
                              void* d_out, int out_size, void* d_ws, size_t ws_size,
                              hipStream_t stream) {
    const float* emb  = (const float*)d_in[0];
    const float* slow = (const float*)d_in[1];
    const float* fast = (const float*)d_in[2];
    const float* W    = (const float*)d_in[3];
    const float* bias = (const float*)d_in[4];
    const int*   ids  = (const int*)d_in[5];

    float* out = (float*)d_out;
    float* nf  = out + (size_t)NROWS * HDIM;
    float* ns  = nf + (size_t)NENT * HDIM;

    // ws layout: Wp 1 MiB | counts/cursor 400 KB | offsets 400 KB | bsums | rowidx 1 MiB
    unsigned short* Wp   = (unsigned short*)d_ws;
    unsigned* counts     = (unsigned*)((char*)d_ws + (1u << 20));            // reused as cursor
    unsigned* off        = (unsigned*)((char*)d_ws + (1u << 20) + 512 * 1024);
    unsigned* bsums      = (unsigned*)((char*)d_ws + (2u << 20));
    int*      rowidx     = (int*)((char*)d_ws + (2u << 20) + 4096);

    hipMemsetAsync(counts, 0, (size_t)NENT * sizeof(unsigned), stream);

    pack_w_kernel<<<256, 256, 0, stream>>>(W, Wp);
    count_kernel<<<NROWS / 256, 256, 0, stream>>>(ids, counts);
    scan1_kernel<<<SCAN_NBLK, 1024, 0, stream>>>(counts, off, bsums);
    scan2_kernel<<<1, 64, 0, stream>>>(bsums);
    scan3_kernel<<<SCAN_NBLK, 1024, 0, stream>>>(off, bsums, counts);
    fill_kernel<<<NROWS / 256, 256, 0, stream>>>(ids, counts, rowidx);
    fuse_kernel<<<NROWS / 64, 1024, 0, stream>>>(emb, slow, Wp, bias, ids, out);
    finalize_kernel<<<(NENT + 3) / 4, 256, 0, stream>>>(fast, slow, out, off, rowidx, nf, ns);
}

// Round 6
// 941.818 us; speedup vs baseline: 1.1078x; 1.0402x over previous
//
#include <hip/hip_runtime.h>
#include <hip/hip_bf16.h>
#include <cstdint>

#define NROWS 262144
#define HDIM  512
#define NENT  100000
#define SCAN_NBLK ((NENT + 1023) / 1024)

typedef __attribute__((ext_vector_type(4))) float  f32x4;
typedef __attribute__((ext_vector_type(8))) short  bf16x8;

static __device__ __forceinline__ unsigned short f2bf(float x) {
    unsigned u = __float_as_uint(x);
    u += 0x7FFF + ((u >> 16) & 1);          // round-to-nearest-even
    return (unsigned short)(u >> 16);
}
static __device__ __forceinline__ float bf2f(unsigned short h) {
    unsigned u = ((unsigned)h) << 16;
    return __uint_as_float(u);
}

// Pack W ([512][1024] row-major, y = x @ W.T) into bf16 MFMA *A*-fragment order:
// for (ntile, kt32): lane l holds A[m = nt*16+(l&15)][k = kt*32+(l>>4)*8+j].
__global__ void pack_w_kernel(const float* __restrict__ W, unsigned short* __restrict__ Wp) {
    int g    = blockIdx.x * 256 + threadIdx.x;   // 65536 total
    int lane = g & 63;
    int task = g >> 6;                            // 0..1023 = nt*32 + kt
    int nt   = task >> 5;
    int kt   = task & 31;
    int col  = nt * 16 + (lane & 15);
    int k    = kt * 32 + ((lane >> 4) << 3);
    const float* src = W + (size_t)col * 1024 + k;
    f32x4 v0 = *(const f32x4*)(src);
    f32x4 v1 = *(const f32x4*)(src + 4);
    bf16x8 ov;
#pragma unroll
    for (int i = 0; i < 4; ++i) {
        ov[i]     = (short)f2bf(v0[i]);
        ov[4 + i] = (short)f2bf(v1[i]);
    }
    *(bf16x8*)(Wp + (size_t)g * 8) = ov;
}

// ---- CSR build: counts -> 2-level exclusive scan -> fill row indices ----
__global__ __launch_bounds__(256) void count_kernel(const int* __restrict__ ids,
                                                    unsigned* __restrict__ counts) {
    int r = blockIdx.x * 256 + threadIdx.x;
    if (r < NROWS) atomicAdd(&counts[ids[r]], 1u);
}

__global__ __launch_bounds__(1024) void scan1_kernel(const unsigned* __restrict__ counts,
                                                     unsigned* __restrict__ off,
                                                     unsigned* __restrict__ bsums) {
    __shared__ unsigned tmp[1024];
    int i = blockIdx.x * 1024 + threadIdx.x;
    unsigned v = (i < NENT) ? counts[i] : 0u;
    tmp[threadIdx.x] = v;
    __syncthreads();
#pragma unroll
    for (int o = 1; o < 1024; o <<= 1) {
        unsigned a = (threadIdx.x >= o) ? tmp[threadIdx.x - o] : 0u;
        __syncthreads();
        tmp[threadIdx.x] += a;
        __syncthreads();
    }
    if (i < NENT) off[i] = tmp[threadIdx.x] - v;     // block-local exclusive
    if (threadIdx.x == 1023) bsums[blockIdx.x] = tmp[1023];
}

__global__ void scan2_kernel(unsigned* __restrict__ bsums) {
    if (threadIdx.x == 0 && blockIdx.x == 0) {
        unsigned s = 0;
        for (int i = 0; i < SCAN_NBLK; ++i) { unsigned t = bsums[i]; bsums[i] = s; s += t; }
    }
}

__global__ __launch_bounds__(1024) void scan3_kernel(unsigned* __restrict__ off,
                                                     const unsigned* __restrict__ bsums,
                                                     unsigned* __restrict__ cursor) {
    int i = blockIdx.x * 1024 + threadIdx.x;
    if (i < NENT) {
        unsigned o = off[i] + bsums[blockIdx.x];
        off[i] = o;
        cursor[i] = o;
    }
    if (i == 0) off[NENT] = NROWS;
}

__global__ __launch_bounds__(256) void fill_kernel(const int* __restrict__ ids,
                                                   unsigned* __restrict__ cursor,
                                                   int* __restrict__ rowidx) {
    int r = blockIdx.x * 256 + threadIdx.x;
    if (r < NROWS) {
        unsigned p = atomicAdd(&cursor[ids[r]], 1u);
        rowidx[p] = r;
    }
}

// Fused gate path v3: 32 rows/block x 512 cols. Whole K = [emb | LN(state)]
// staged ONCE as bf16 fragments in LDS (64 KB -> 2 blocks/CU), then a
// BARRIER-FREE K-loop: per wave (32 rows x 64 cols), 32 k-tiles of
// {4 W-frag L2 loads + 2 ds_reads + 8 MFMA}, manual 2-stage reg dbuf.
// Epilogue reads emb/h back from LDS (bf16) -> no global re-reads.
// LDS x layout: tile T = kt*2 + rt; lane l holds rows rt*16+(l&15),
// k = kt*32+(l>>4)*8 .. +7, at bf16x8 slot (T*64+l).
__global__ __launch_bounds__(512, 4) void fuse_kernel(
    const float* __restrict__ emb, const float* __restrict__ slow,
    const unsigned short* __restrict__ Wp, const float* __restrict__ bias,
    const int* __restrict__ ids, float* __restrict__ out)
{
    __shared__ unsigned short xLds[64 * 64 * 8];   // 64 KB
    __shared__ float muS[32], rsS[32], actS[32], bS[512];
    __shared__ int idS[32];

    const int t    = threadIdx.x;
    const int w    = t >> 6;          // 0..7
    const int lane = t & 63;
    const int brow = blockIdx.x * 32;

    if (t < 128) ((f32x4*)bS)[t] = ((const f32x4*)bias)[t];

    // ---- LN stats + is_active: 8 waves x 4 rows ----
    for (int rr = 0; rr < 4; ++rr) {
        int row = w * 4 + rr;
        int id  = ids[brow + row];
        const float* sp = slow + (size_t)id * HDIM;
        f32x4 v0 = ((const f32x4*)sp)[lane * 2];
        f32x4 v1 = ((const f32x4*)sp)[lane * 2 + 1];
        float s = 0.f, s2 = 0.f, sa = 0.f;
#pragma unroll
        for (int i = 0; i < 4; ++i) {
            s  += v0[i] + v1[i];
            s2 += v0[i] * v0[i] + v1[i] * v1[i];
            sa += fabsf(v0[i]) + fabsf(v1[i]);
        }
#pragma unroll
        for (int m = 32; m >= 1; m >>= 1) {
            s  += __shfl_xor(s, m);
            s2 += __shfl_xor(s2, m);
            sa += __shfl_xor(sa, m);
        }
        if (lane == 0) {
            float mu  = s * (1.f / HDIM);
            float var = s2 * (1.f / HDIM) - mu * mu;
            muS[row]  = mu;
            rsS[row]  = rsqrtf(var + 1e-5f);
            actS[row] = (sa > 1e-6f) ? 1.f : 0.f;
            idS[row]  = id;
        }
    }
    __syncthreads();

    // ---- stage whole K as bf16 fragments: 4096 lane-slots / 512 threads ----
    for (int slot = t; slot < 4096; slot += 512) {
        int T    = slot >> 6;
        int ls   = slot & 63;
        int kt   = T >> 1;
        int row  = (T & 1) * 16 + (ls & 15);
        int k    = kt * 32 + ((ls >> 4) << 3);
        f32x4 x0, x1;
        if (k < 512) {
            const float* p = emb + (size_t)(brow + row) * HDIM + k;
            x0 = *(const f32x4*)p;
            x1 = *(const f32x4*)(p + 4);
        } else {
            const float* p = slow + (size_t)idS[row] * HDIM + (k - 512);
            x0 = *(const f32x4*)p;
            x1 = *(const f32x4*)(p + 4);
            float mu = muS[row], rs = rsS[row];
#pragma unroll
            for (int i = 0; i < 4; ++i) {
                x0[i] = (x0[i] - mu) * rs;
                x1[i] = (x1[i] - mu) * rs;
            }
        }
        bf16x8 av;
#pragma unroll
        for (int i = 0; i < 4; ++i) {
            av[i]     = (short)f2bf(x0[i]);
            av[4 + i] = (short)f2bf(x1[i]);
        }
        ((bf16x8*)xLds)[slot] = av;
    }
    __syncthreads();

    // ---- barrier-free K loop: wave w covers cols w*64..w*64+63 ----
    f32x4 zero4 = {0.f, 0.f, 0.f, 0.f};
    f32x4 acc[2][4];                    // [rt][ct]
#pragma unroll
    for (int i = 0; i < 2; ++i)
#pragma unroll
        for (int j = 0; j < 4; ++j) acc[i][j] = zero4;

    const unsigned short* wpL = Wp + (size_t)lane * 8;   // + ((nt*32+kt)*64)*8

#define LOADW(dst, kt)                                                  \
    _Pragma("unroll")                                                   \
    for (int ct = 0; ct < 4; ++ct)                                      \
        dst[ct] = *(const bf16x8*)(wpL + ((size_t)((w * 4 + ct) * 32 + (kt)) << 9));

#define LOADX(dst, kt)                                                  \
    _Pragma("unroll")                                                   \
    for (int rt = 0; rt < 2; ++rt)                                      \
        dst[rt] = ((const bf16x8*)xLds)[((kt) * 2 + rt) * 64 + lane];

#define MFMA_STEP(wf, xf)                                               \
    _Pragma("unroll")                                                   \
    for (int ct = 0; ct < 4; ++ct) {                                    \
        acc[0][ct] = __builtin_amdgcn_mfma_f32_16x16x32_bf16(wf[ct], xf[0], acc[0][ct], 0, 0, 0); \
        acc[1][ct] = __builtin_amdgcn_mfma_f32_16x16x32_bf16(wf[ct], xf[1], acc[1][ct], 0, 0, 0); \
    }

    bf16x8 wA[4], wB[4], xA[2], xB[2];
    LOADW(wA, 0);
    LOADX(xA, 0);
    for (int kt = 0; kt < 32; kt += 2) {
        if (kt + 1 < 32) { LOADW(wB, kt + 1); LOADX(xB, kt + 1); }
        MFMA_STEP(wA, xA);
        if (kt + 2 < 32) { LOADW(wA, kt + 2); LOADX(xA, kt + 2); }
        if (kt + 1 < 32) MFMA_STEP(wB, xB);
    }
#undef LOADW
#undef LOADX
#undef MFMA_STEP

    // ---- epilogue: bias+sigmoid+fuse; emb/h from LDS (bf16); f32x4 store ----
#pragma unroll
    for (int rt = 0; rt < 2; ++rt) {
        int rowl = rt * 16 + (lane & 15);
        int grow = brow + rowl;
        float mu = muS[rowl], rs = rsS[rowl], act = actS[rowl];
        (void)mu; (void)rs;
        float* outP = out + (size_t)grow * HDIM;
#pragma unroll
        for (int ct = 0; ct < 4; ++ct) {
            int col0 = w * 64 + ct * 16 + ((lane >> 4) << 2);
            // emb[row][col0..3] from LDS: k = col0
            int Te = ((col0 >> 5) * 2 + rt) * 64 + (((col0 >> 3) & 3) << 4) + (lane & 15);
            const unsigned short* pe = xLds + Te * 8 + (col0 & 7);
            // h[row][col0..3] from LDS: k = 512 + col0
            int kh = 512 + col0;
            int Th = ((kh >> 5) * 2 + rt) * 64 + (((kh >> 3) & 3) << 4) + (lane & 15);
            const unsigned short* ph = xLds + Th * 8 + (kh & 7);
            f32x4 bv = *(const f32x4*)&bS[col0];
            f32x4 o;
#pragma unroll
            for (int r = 0; r < 4; ++r) {
                float ev = bf2f(pe[r]);
                float hv = bf2f(ph[r]);
                float logit = acc[rt][ct][r] + bv[r];
                float z  = 1.f / (1.f + __expf(-logit));
                float fused = z * ev + (1.f - z) * hv;
                o[r] = (act > 0.f) ? fused : ev;
            }
            *(f32x4*)(outP + col0) = o;
        }
    }
}

// Per-entity: gather its rows from `out` (CSR), mean -> EMA fast, norm-gated slow.
__global__ __launch_bounds__(256) void finalize_kernel(
    const float* __restrict__ fast, const float* __restrict__ slow,
    const float* __restrict__ out, const unsigned* __restrict__ off,
    const int* __restrict__ rowidx, float* __restrict__ nf, float* __restrict__ ns)
{
    int e = blockIdx.x * 4 + (threadIdx.x >> 6);
    if (e >= NENT) return;
    int lane = threadIdx.x & 63;
    size_t base = (size_t)e * HDIM + lane * 8;

    f32x4 f0 = *(const f32x4*)(fast + base), f1 = *(const f32x4*)(fast + base + 4);
    f32x4 l0 = *(const f32x4*)(slow + base), l1 = *(const f32x4*)(slow + base + 4);

    unsigned o0 = off[e], o1 = off[e + 1];
    int c = (int)(o1 - o0);

    if (c == 0) {
        *(f32x4*)(nf + base)     = f0;
        *(f32x4*)(nf + base + 4) = f1;
        *(f32x4*)(ns + base)     = l0;
        *(f32x4*)(ns + base + 4) = l1;
        return;
    }

    f32x4 s0 = {0.f, 0.f, 0.f, 0.f}, s1 = {0.f, 0.f, 0.f, 0.f};
    for (int j = 0; j < c; ++j) {
        int r = rowidx[o0 + j];
        const float* p = out + (size_t)r * HDIM + lane * 8;
        s0 += *(const f32x4*)p;
        s1 += *(const f32x4*)(p + 4);
    }

    float inv = 0.5f / (float)c;          // ALPHA / count
    f32x4 n0, n1, d0, d1;
    float ss = 0.f;
#pragma unroll
    for (int i = 0; i < 4; ++i) {
        n0[i] = 0.5f * f0[i] + s0[i] * inv;
        n1[i] = 0.5f * f1[i] + s1[i] * inv;
        d0[i] = n0[i] - l0[i]; ss += d0[i] * d0[i];
        d1[i] = n1[i] - l1[i]; ss += d1[i] * d1[i];
    }
#pragma unroll
    for (int m = 32; m >= 1; m >>= 1) ss += __shfl_xor(ss, m);
    float delta = sqrtf(ss);
    float gate  = 1.f / (1.f + expf(-5.f * (delta - 0.5f)));

    f32x4 o0v, o1v;
#pragma unroll
    for (int i = 0; i < 4; ++i) {
        o0v[i] = l0[i] + gate * d0[i];
        o1v[i] = l1[i] + gate * d1[i];
    }
    *(f32x4*)(nf + base)     = n0;
    *(f32x4*)(nf + base + 4) = n1;
    *(f32x4*)(ns + base)     = o0v;
    *(f32x4*)(ns + base + 4) = o1v;
}

extern "C" void kernel_launch(void* const* d_in, const int* in_sizes, int n_in,
                              void* d_out, int out_size, void* d_ws, size_t ws_size,
                              hipStream_t stream) {
    const float* emb  = (const float*)d_in[0];
    const float* slow = (const float*)d_in[1];
    const float* fast = (const float*)d_in[2];
    const float* W    = (const float*)d_in[3];
    const float* bias = (const float*)d_in[4];
    const int*   ids  = (const int*)d_in[5];

    float* out = (float*)d_out;
    float* nf  = out + (size_t)NROWS * HDIM;
    float* ns  = nf + (size_t)NENT * HDIM;

    // ws layout: Wp 1 MiB | counts/cursor 400 KB | offsets 400 KB | bsums | rowidx 1 MiB
    unsigned short* Wp   = (unsigned short*)d_ws;
    unsigned* counts     = (unsigned*)((char*)d_ws + (1u << 20));            // reused as cursor
    unsigned* off        = (unsigned*)((char*)d_ws + (1u << 20) + 512 * 1024);
    unsigned* bsums      = (unsigned*)((char*)d_ws + (2u << 20));
    int*      rowidx     = (int*)((char*)d_ws + (2u << 20) + 4096);

    hipMemsetAsync(counts, 0, (size_t)NENT * sizeof(unsigned), stream);

    pack_w_kernel<<<256, 256, 0, stream>>>(W, Wp);
    count_kernel<<<NROWS / 256, 256, 0, stream>>>(ids, counts);
    scan1_kernel<<<SCAN_NBLK, 1024, 0, stream>>>(counts, off, bsums);
    scan2_kernel<<<1, 64, 0, stream>>>(bsums);
    scan3_kernel<<<SCAN_NBLK, 1024, 0, stream>>>(off, bsums, counts);
    fill_kernel<<<NROWS / 256, 256, 0, stream>>>(ids, counts, rowidx);
    fuse_kernel<<<NROWS / 32, 512, 0, stream>>>(emb, slow, Wp, bias, ids, out);
    finalize_kernel<<<(NENT + 3) / 4, 256, 0, stream>>>(fast, slow, out, off, rowidx, nf, ns);
}